// Round 11
// baseline (277.327 us; speedup 1.0000x reference)
//
#include <hip/hip_runtime.h>

// DIM=256 H=8 HD=32 W=64 N=8192 nw=128
// xyz: T=40, off=20, hi=39, R=120 (pad 128) ; rgb: T=32, off=16, hi=31, R=96
// table element ((c*T+t)*8+h)*32+d == r*256 + h*32 + d, r=c*T+t

typedef __attribute__((ext_vector_type(8))) short short8;
typedef __attribute__((ext_vector_type(4))) float f32x4;

__device__ __forceinline__ unsigned short f2bf(float f) {
    union { float f; unsigned int u; } v; v.f = f;
    unsigned int r = v.u + 0x7FFFu + ((v.u >> 16) & 1u);
    return (unsigned short)(r >> 16);
}
__device__ __forceinline__ float bf2f(ushort u) {
    union { unsigned int u; float f; } v; v.u = ((unsigned int)u) << 16;
    return v.f;
}

// ---------------------------------------------------------------------------
// QKV GEMM (bf16 MFMA), fp32 inputs cast inline during staging.
// ---------------------------------------------------------------------------
__global__ __launch_bounds__(256) void k_qkv(
    const float* __restrict__ A, const float* __restrict__ B,
    const float* __restrict__ bias,
    ushort* __restrict__ qb, ushort* __restrict__ kb, ushort* __restrict__ vb)
{
    __shared__ __align__(16) ushort a_s[128 * 72];
    __shared__ __align__(16) ushort b_s[64 * 72];
    const int tid = threadIdx.x;
    const int m0 = blockIdx.y * 128;
    const int n0 = blockIdx.x * 64;
    const int w = tid >> 6, wm = w >> 1, wn = w & 1;
    const int l4 = tid & 15, quad = (tid >> 4) & 3;
    f32x4 acc[4][2];
#pragma unroll
    for (int mt = 0; mt < 4; ++mt)
#pragma unroll
        for (int nt = 0; nt < 2; ++nt) acc[mt][nt] = (f32x4){0.f, 0.f, 0.f, 0.f};

    for (int k0 = 0; k0 < 256; k0 += 64) {
#pragma unroll
        for (int l = 0; l < 4; ++l) {
            int e = tid + l * 256;
            int row = e >> 3, kq = e & 7;
            const float* ap = A + (size_t)(m0 + row) * 256 + k0 + kq * 8;
            float4 v0 = *(const float4*)ap, v1 = *(const float4*)(ap + 4);
            union { ushort u[8]; uint4 v; } pk;
            pk.u[0] = f2bf(v0.x); pk.u[1] = f2bf(v0.y); pk.u[2] = f2bf(v0.z); pk.u[3] = f2bf(v0.w);
            pk.u[4] = f2bf(v1.x); pk.u[5] = f2bf(v1.y); pk.u[6] = f2bf(v1.z); pk.u[7] = f2bf(v1.w);
            *(uint4*)&a_s[row * 72 + kq * 8] = pk.v;
        }
#pragma unroll
        for (int l = 0; l < 2; ++l) {
            int e = tid + l * 256;
            int row = e >> 3, kq = e & 7;
            const float* bp = B + (size_t)(n0 + row) * 256 + k0 + kq * 8;
            float4 v0 = *(const float4*)bp, v1 = *(const float4*)(bp + 4);
            union { ushort u[8]; uint4 v; } pk;
            pk.u[0] = f2bf(v0.x); pk.u[1] = f2bf(v0.y); pk.u[2] = f2bf(v0.z); pk.u[3] = f2bf(v0.w);
            pk.u[4] = f2bf(v1.x); pk.u[5] = f2bf(v1.y); pk.u[6] = f2bf(v1.z); pk.u[7] = f2bf(v1.w);
            *(uint4*)&b_s[row * 72 + kq * 8] = pk.v;
        }
        __syncthreads();
#pragma unroll
        for (int kh = 0; kh < 2; ++kh) {
            short8 bf0 = *(const short8*)&b_s[(wn * 32 + l4) * 72 + kh * 32 + quad * 8];
            short8 bf1 = *(const short8*)&b_s[(wn * 32 + 16 + l4) * 72 + kh * 32 + quad * 8];
#pragma unroll
            for (int mt = 0; mt < 4; ++mt) {
                short8 af = *(const short8*)&a_s[(wm * 64 + mt * 16 + l4) * 72 + kh * 32 + quad * 8];
                acc[mt][0] = __builtin_amdgcn_mfma_f32_16x16x32_bf16(af, bf0, acc[mt][0], 0, 0, 0);
                acc[mt][1] = __builtin_amdgcn_mfma_f32_16x16x32_bf16(af, bf1, acc[mt][1], 0, 0, 0);
            }
        }
        __syncthreads();
    }
#pragma unroll
    for (int nt = 0; nt < 2; ++nt) {
        int c = n0 + wn * 32 + nt * 16 + l4;
        float bv = bias[c];
        int s = c >> 8, rem = c & 255, h = rem >> 5, d = rem & 31;
        ushort* dst = (s == 0) ? qb : ((s == 1) ? kb : vb);
        float mul = (s == 0) ? 0.17677669529663687f : 1.0f;
#pragma unroll
        for (int mt = 0; mt < 4; ++mt) {
            int mbase = m0 + wm * 64 + mt * 16 + quad * 4;
#pragma unroll
            for (int reg = 0; reg < 4; ++reg) {
                int m = mbase + reg;
                int nw = m >> 6, ii = m & 63;
                dst[((size_t)((nw * 8 + h) * 64 + ii)) * 32 + d] = f2bf((acc[mt][nt][reg] + bv) * mul);
            }
        }
    }
}

// ---------------------------------------------------------------------------
// MFMA attention per (window, head). Round-10 register discipline
// ((256,2), no idx arrays — recompute from LDS cwf) + LDS cut to EXACTLY
// 40,960 B -> 4 blocks/CU (was 55,296 -> 2): dbuf is bf16, AV serialized
// before the bins phase so attn_s/v_t never coexist with bins/vtbl.
// LDS map (ushort offsets in L[20480]):
//   Phase A: q_s@0[64][40], k_s@2560, tbl@5120[128][40],
//            dbufB@10240 bf16[64][122] -> [10240,18048)
//   Phase B1 (softmax+AV): attn_s@0[64][72], v_t@4608[32][68] -> [4608,6784)
//   Phase B2 (bins):       bins fp32[64][120]@0 -> [0,15360),
//                          vtbl@15360[32][130] -> [15360,19520)
//   cwf fp32[64][6]@19712 (alive whole kernel).  Total 40,960 B.
// Spill tripwire: WRITE_SIZE >> 4.1 MB means registers no longer fit.
// ---------------------------------------------------------------------------
__global__ __launch_bounds__(256, 2) void k_attn(
    const ushort* __restrict__ qb, const ushort* __restrict__ kb, const ushort* __restrict__ vb,
    const float* __restrict__ nco,
    const float* __restrict__ qxt, const float* __restrict__ kxt, const float* __restrict__ vxt,
    const float* __restrict__ qrt, const float* __restrict__ krt, const float* __restrict__ vrt,
    ushort* __restrict__ aout)
{
    __shared__ __align__(16) ushort L[20480];
    ushort* q_s   = L;                     // [64][40]
    ushort* k_s   = L + 2560;              // [64][40]
    ushort* tbl   = L + 5120;              // [128][40]
    ushort* dbufB = L + 10240;             // bf16 [64][122]
    ushort* attn_s = L;                    // [64][72]
    ushort* v_t    = L + 4608;             // [32][68]
    float*  bins   = (float*)L;            // [64][120]
    ushort* vtbl   = L + 15360;            // [32][130]
    float*  cwf    = (float*)(L + 19712);  // [64][6]

    const int tid = threadIdx.x;
    const int n = blockIdx.x >> 3;
    const int h = blockIdx.x & 7;
    const int w = tid >> 6;
    const int l4 = tid & 15;
    const int quad = (tid >> 4) & 3;

    const size_t base = (size_t)((n * 8 + h) * 64) * 32;

    // ---- seg 1: stage q, k, coords, tbl(kxt) ----
    {
        int row = tid >> 2, part = tid & 3;
        *(uint4*)&q_s[row * 40 + part * 8] = *(const uint4*)(qb + base + tid * 8);
        *(uint4*)&k_s[row * 40 + part * 8] = *(const uint4*)(kb + base + tid * 8);
    }
    if (tid < 64) {
        const float* cp = nco + (size_t)(n * 64 + tid) * 6;
        cwf[tid * 6 + 0] = cp[0] * 4.f; cwf[tid * 6 + 1] = cp[1] * 4.f;
        cwf[tid * 6 + 2] = cp[2] * 4.f; cwf[tid * 6 + 3] = cp[3] * 8.f;
        cwf[tid * 6 + 4] = cp[4] * 8.f; cwf[tid * 6 + 5] = cp[5] * 8.f;
    }

    auto stageTbl = [&](const float* tbg, int R, int Rpad) {
        for (int e = tid; e < R * 4; e += 256) {
            int r = e >> 2, part = e & 3;
            const float* src = tbg + (size_t)r * 256 + part * 8;
            float4 f0 = *(const float4*)src, f1 = *(const float4*)(src + 4);
            union { ushort u[8]; uint4 v; } pk;
            pk.u[0] = f2bf(f0.x); pk.u[1] = f2bf(f0.y); pk.u[2] = f2bf(f0.z); pk.u[3] = f2bf(f0.w);
            pk.u[4] = f2bf(f1.x); pk.u[5] = f2bf(f1.y); pk.u[6] = f2bf(f1.z); pk.u[7] = f2bf(f1.w);
            *(uint4*)&tbl[r * 40 + part * 8] = pk.v;
        }
        for (int e = tid; e < (Rpad - R) * 40; e += 256) tbl[R * 40 + e] = 0;
    };
    auto stageVtbl = [&](const float* tbg, int R) {
        for (int e = tid; e < R * 4; e += 256) {
            int r = e >> 2, part = e & 3;
            const float* src = tbg + (size_t)r * 256 + part * 8;
            float4 f0 = *(const float4*)src, f1 = *(const float4*)(src + 4);
            int d0 = part * 8;
            vtbl[(d0 + 0) * 130 + r] = f2bf(f0.x);
            vtbl[(d0 + 1) * 130 + r] = f2bf(f0.y);
            vtbl[(d0 + 2) * 130 + r] = f2bf(f0.z);
            vtbl[(d0 + 3) * 130 + r] = f2bf(f0.w);
            vtbl[(d0 + 4) * 130 + r] = f2bf(f1.x);
            vtbl[(d0 + 5) * 130 + r] = f2bf(f1.y);
            vtbl[(d0 + 6) * 130 + r] = f2bf(f1.z);
            vtbl[(d0 + 7) * 130 + r] = f2bf(f1.w);
        }
        int span = 128 - R;
        for (int e = tid; e < 32 * span; e += 256) {
            int d = e / span, rr = e - d * span;
            vtbl[d * 130 + R + rr] = 0;
        }
    };
    auto stageVt = [&]() {
        int j = tid >> 2, d0 = (tid & 3) * 8;
        uint4 pk = *(const uint4*)(vb + base + tid * 8);
        const ushort* u = (const ushort*)&pk;
#pragma unroll
        for (int ii = 0; ii < 8; ++ii) v_t[(d0 + ii) * 68 + j] = u[ii];
    };

    auto tgemm = [&](const ushort* a_s, int NT, int maxc) {
        short8 af = *(const short8*)&a_s[(w * 16 + l4) * 40 + quad * 8];
        for (int tt = 0; tt < NT; ++tt) {
            short8 bf = *(const short8*)&tbl[(tt * 16 + l4) * 40 + quad * 8];
            f32x4 a = {0.f, 0.f, 0.f, 0.f};
            a = __builtin_amdgcn_mfma_f32_16x16x32_bf16(af, bf, a, 0, 0, 0);
            int col = tt * 16 + l4;
            int rb = w * 16 + quad * 4;
            if (col < maxc) {
                dbufB[(rb + 0) * 122 + col] = f2bf(a[0]);
                dbufB[(rb + 1) * 122 + col] = f2bf(a[1]);
                dbufB[(rb + 2) * 122 + col] = f2bf(a[2]);
                dbufB[(rb + 3) * 122 + col] = f2bf(a[3]);
            }
        }
    };

    stageTbl(kxt + h * 32, 120, 128);
    __syncthreads();

    float lg[4][4];   // [tt][reg]: row i = w*16+quad*4+reg, col j = tt*16+l4

    // Indices recomputed from cwf at every use site (no idx register arrays).
    auto gatherX = [&](bool useJ) {
#pragma unroll
        for (int tt = 0; tt < 4; ++tt) {
            int j = tt * 16 + l4;
            float cj0 = cwf[j * 6 + 0], cj1 = cwf[j * 6 + 1], cj2 = cwf[j * 6 + 2];
#pragma unroll
            for (int reg = 0; reg < 4; ++reg) {
                int i = w * 16 + quad * 4 + reg;
                int x0 = min(max((int)floorf(cwf[i * 6 + 0] - cj0) + 20, 0), 39);
                int x1 = min(max((int)floorf(cwf[i * 6 + 1] - cj1) + 20, 0), 39);
                int x2 = min(max((int)floorf(cwf[i * 6 + 2] - cj2) + 20, 0), 39);
                int b = (useJ ? j : i) * 122;
                lg[tt][reg] += bf2f(dbufB[b + x0]) + bf2f(dbufB[b + 40 + x1])
                             + bf2f(dbufB[b + 80 + x2]);
            }
        }
    };
    auto gatherR = [&](bool useJ) {
#pragma unroll
        for (int tt = 0; tt < 4; ++tt) {
            int j = tt * 16 + l4;
            float cj3 = cwf[j * 6 + 3], cj4 = cwf[j * 6 + 4], cj5 = cwf[j * 6 + 5];
#pragma unroll
            for (int reg = 0; reg < 4; ++reg) {
                int i = w * 16 + quad * 4 + reg;
                int r0 = min(max((int)floorf(cwf[i * 6 + 3] - cj3) + 16, 0), 31);
                int r1 = min(max((int)floorf(cwf[i * 6 + 4] - cj4) + 16, 0), 31);
                int r2 = min(max((int)floorf(cwf[i * 6 + 5] - cj5) + 16, 0), 31);
                int b = (useJ ? j : i) * 122;
                lg[tt][reg] += bf2f(dbufB[b + r0]) + bf2f(dbufB[b + 32 + r1])
                             + bf2f(dbufB[b + 64 + r2]);
            }
        }
    };
    auto scatterX = [&]() {
#pragma unroll
        for (int tt = 0; tt < 4; ++tt) {
            int j = tt * 16 + l4;
            float cj0 = cwf[j * 6 + 0], cj1 = cwf[j * 6 + 1], cj2 = cwf[j * 6 + 2];
#pragma unroll
            for (int reg = 0; reg < 4; ++reg) {
                int i = w * 16 + quad * 4 + reg;
                int x0 = min(max((int)floorf(cwf[i * 6 + 0] - cj0) + 20, 0), 39);
                int x1 = min(max((int)floorf(cwf[i * 6 + 1] - cj1) + 20, 0), 39);
                int x2 = min(max((int)floorf(cwf[i * 6 + 2] - cj2) + 20, 0), 39);
                float* bi = &bins[i * 120];
                float a = lg[tt][reg];
                atomicAdd(bi + x0, a);
                atomicAdd(bi + 40 + x1, a);
                atomicAdd(bi + 80 + x2, a);
            }
        }
    };
    auto scatterR = [&]() {
#pragma unroll
        for (int tt = 0; tt < 4; ++tt) {
            int j = tt * 16 + l4;
            float cj3 = cwf[j * 6 + 3], cj4 = cwf[j * 6 + 4], cj5 = cwf[j * 6 + 5];
#pragma unroll
            for (int reg = 0; reg < 4; ++reg) {
                int i = w * 16 + quad * 4 + reg;
                int r0 = min(max((int)floorf(cwf[i * 6 + 3] - cj3) + 16, 0), 31);
                int r1 = min(max((int)floorf(cwf[i * 6 + 4] - cj4) + 16, 0), 31);
                int r2 = min(max((int)floorf(cwf[i * 6 + 5] - cj5) + 16, 0), 31);
                float* bi = &bins[i * 120];
                float a = lg[tt][reg];
                atomicAdd(bi + r0, a);
                atomicAdd(bi + 32 + r1, a);
                atomicAdd(bi + 64 + r2, a);
            }
        }
    };
    auto zeroBins = [&]() {
        float4 z = {0.f, 0.f, 0.f, 0.f};
        for (int e = tid * 4; e < 64 * 120; e += 1024) *(float4*)&bins[e] = z;
    };

    // ---- seg 2: QK logits + dk_xyz ----
    {
        short8 aq = *(const short8*)&q_s[(w * 16 + l4) * 40 + quad * 8];
#pragma unroll
        for (int tt = 0; tt < 4; ++tt) {
            short8 bk = *(const short8*)&k_s[(tt * 16 + l4) * 40 + quad * 8];
            f32x4 r = {0.f, 0.f, 0.f, 0.f};
            r = __builtin_amdgcn_mfma_f32_16x16x32_bf16(aq, bk, r, 0, 0, 0);
            lg[tt][0] = r[0]; lg[tt][1] = r[1]; lg[tt][2] = r[2]; lg[tt][3] = r[3];
        }
    }
    tgemm(k_s, 8, 120);                  // dk_xyz
    __syncthreads();
    gatherX(true);                       // bias_k xyz
    stageTbl(krt + h * 32, 96, 96);
    __syncthreads();
    tgemm(k_s, 6, 96);                   // dk_rgb
    __syncthreads();
    gatherR(true);                       // bias_k rgb
    stageTbl(qxt + h * 32, 120, 128);
    __syncthreads();
    tgemm(q_s, 8, 120);                  // dq_xyz
    __syncthreads();
    gatherX(false);                      // bias_q xyz
    stageTbl(qrt + h * 32, 96, 96);
    __syncthreads();
    tgemm(q_s, 6, 96);                   // dq_rgb
    __syncthreads();
    gatherR(false);                      // bias_q rgb
    stageVt();                           // v_t over dead k_s tail / tbl head
    __syncthreads();

    // ---- seg 10: softmax + attn_s write + AV (same-wave rows, no barrier) ----
#pragma unroll
    for (int reg = 0; reg < 4; ++reg) {
        float m = fmaxf(fmaxf(lg[0][reg], lg[1][reg]), fmaxf(lg[2][reg], lg[3][reg]));
        m = fmaxf(m, __shfl_xor(m, 1));
        m = fmaxf(m, __shfl_xor(m, 2));
        m = fmaxf(m, __shfl_xor(m, 4));
        m = fmaxf(m, __shfl_xor(m, 8));
        float s = 0.f;
#pragma unroll
        for (int tt = 0; tt < 4; ++tt) { lg[tt][reg] = __expf(lg[tt][reg] - m); s += lg[tt][reg]; }
        s += __shfl_xor(s, 1); s += __shfl_xor(s, 2);
        s += __shfl_xor(s, 4); s += __shfl_xor(s, 8);
        float inv = 1.f / s;
#pragma unroll
        for (int tt = 0; tt < 4; ++tt) lg[tt][reg] *= inv;
    }
#pragma unroll
    for (int tt = 0; tt < 4; ++tt)
#pragma unroll
        for (int reg = 0; reg < 4; ++reg)
            attn_s[(w * 16 + quad * 4 + reg) * 72 + tt * 16 + l4] = f2bf(lg[tt][reg]);

    f32x4 acc0 = {0.f, 0.f, 0.f, 0.f}, acc1 = {0.f, 0.f, 0.f, 0.f};
#pragma unroll
    for (int s = 0; s < 2; ++s) {
        short8 af = *(const short8*)&attn_s[(w * 16 + l4) * 72 + s * 32 + quad * 8];
        short8 b0 = *(const short8*)&v_t[l4 * 68 + s * 32 + quad * 8];
        short8 b1 = *(const short8*)&v_t[(16 + l4) * 68 + s * 32 + quad * 8];
        acc0 = __builtin_amdgcn_mfma_f32_16x16x32_bf16(af, b0, acc0, 0, 0, 0);
        acc1 = __builtin_amdgcn_mfma_f32_16x16x32_bf16(af, b1, acc1, 0, 0, 0);
    }
    __syncthreads();                     // attn_s/v_t dead; bins region free

    // ---- seg 11..: bins phase (xyz then rgb) ----
    zeroBins();
    stageVtbl(vxt + h * 32, 120);
    __syncthreads();
    scatterX();
    __syncthreads();

    auto atgemm = [&](int Rlim) {
#pragma unroll
        for (int s = 0; s < 4; ++s) {
            int koff = s * 32 + quad * 8;
            short8 af = {0, 0, 0, 0, 0, 0, 0, 0};
            if (koff < Rlim) {
                const float* ap = &bins[(w * 16 + l4) * 120 + koff];
#pragma unroll
                for (int ii = 0; ii < 8; ++ii) af[ii] = (short)f2bf(ap[ii]);
            }
            short8 b0 = *(const short8*)&vtbl[l4 * 130 + koff];
            short8 b1 = *(const short8*)&vtbl[(16 + l4) * 130 + koff];
            acc0 = __builtin_amdgcn_mfma_f32_16x16x32_bf16(af, b0, acc0, 0, 0, 0);
            acc1 = __builtin_amdgcn_mfma_f32_16x16x32_bf16(af, b1, acc1, 0, 0, 0);
        }
    };
    atgemm(120);                         // value-bias xyz
    __syncthreads();
    zeroBins();
    stageVtbl(vrt + h * 32, 96);
    __syncthreads();
    scatterR();
    __syncthreads();
    atgemm(96);                          // value-bias rgb

    // ---- epilogue: bf16 ao[i][h*32+d] ----
    {
        ushort* op = aout + (size_t)(n * 64 + w * 16 + quad * 4) * 256 + h * 32;
#pragma unroll
        for (int reg = 0; reg < 4; ++reg) {
            op[reg * 256 + l4] = f2bf(acc0[reg]);
            op[reg * 256 + 16 + l4] = f2bf(acc1[reg]);
        }
    }
}

// ---------------------------------------------------------------------------
// Proj GEMM (bf16 MFMA): out = ao(bf16) @ proj_w(fp32, cast inline)^T + pb
// ---------------------------------------------------------------------------
__global__ __launch_bounds__(256) void k_proj(
    const ushort* __restrict__ A, const float* __restrict__ B,
    const float* __restrict__ bias, float* __restrict__ out)
{
    __shared__ __align__(16) ushort a_s[128 * 72];
    __shared__ __align__(16) ushort b_s[64 * 72];
    const int tid = threadIdx.x;
    const int m0 = blockIdx.y * 128;
    const int n0 = blockIdx.x * 64;
    const int w = tid >> 6, wm = w >> 1, wn = w & 1;
    const int l4 = tid & 15, quad = (tid >> 4) & 3;
    f32x4 acc[4][2];
#pragma unroll
    for (int mt = 0; mt < 4; ++mt)
#pragma unroll
        for (int nt = 0; nt < 2; ++nt) acc[mt][nt] = (f32x4){0.f, 0.f, 0.f, 0.f};

    for (int k0 = 0; k0 < 256; k0 += 64) {
#pragma unroll
        for (int l = 0; l < 4; ++l) {
            int e = tid + l * 256;
            int row = e >> 3, kq = e & 7;
            *(uint4*)&a_s[row * 72 + kq * 8] =
                *(const uint4*)(A + (size_t)(m0 + row) * 256 + k0 + kq * 8);
        }
#pragma unroll
        for (int l = 0; l < 2; ++l) {
            int e = tid + l * 256;
            int row = e >> 3, kq = e & 7;
            const float* bp = B + (size_t)(n0 + row) * 256 + k0 + kq * 8;
            float4 v0 = *(const float4*)bp, v1 = *(const float4*)(bp + 4);
            union { ushort u[8]; uint4 v; } pk;
            pk.u[0] = f2bf(v0.x); pk.u[1] = f2bf(v0.y); pk.u[2] = f2bf(v0.z); pk.u[3] = f2bf(v0.w);
            pk.u[4] = f2bf(v1.x); pk.u[5] = f2bf(v1.y); pk.u[6] = f2bf(v1.z); pk.u[7] = f2bf(v1.w);
            *(uint4*)&b_s[row * 72 + kq * 8] = pk.v;
        }
        __syncthreads();
#pragma unroll
        for (int kh = 0; kh < 2; ++kh) {
            short8 bf0 = *(const short8*)&b_s[(wn * 32 + l4) * 72 + kh * 32 + quad * 8];
            short8 bf1 = *(const short8*)&b_s[(wn * 32 + 16 + l4) * 72 + kh * 32 + quad * 8];
#pragma unroll
            for (int mt = 0; mt < 4; ++mt) {
                short8 af = *(const short8*)&a_s[(wm * 64 + mt * 16 + l4) * 72 + kh * 32 + quad * 8];
                acc[mt][0] = __builtin_amdgcn_mfma_f32_16x16x32_bf16(af, bf0, acc[mt][0], 0, 0, 0);
                acc[mt][1] = __builtin_amdgcn_mfma_f32_16x16x32_bf16(af, bf1, acc[mt][1], 0, 0, 0);
            }
        }
        __syncthreads();
    }
#pragma unroll
    for (int nt = 0; nt < 2; ++nt) {
        int c = n0 + wn * 32 + nt * 16 + l4;
        float bv = bias[c];
#pragma unroll
        for (int mt = 0; mt < 4; ++mt) {
            int mbase = m0 + wm * 64 + mt * 16 + quad * 4;
#pragma unroll
            for (int reg = 0; reg < 4; ++reg)
                out[(size_t)(mbase + reg) * 256 + c] = acc[mt][nt][reg] + bv;
        }
    }
}

extern "C" void kernel_launch(void* const* d_in, const int* in_sizes, int n_in,
                              void* d_out, int out_size, void* d_ws, size_t ws_size,
                              hipStream_t stream)
{
    const float* feats = (const float*)d_in[0];
    const float* nco   = (const float*)d_in[1];
    const float* qkvw  = (const float*)d_in[2];
    const float* qkvb  = (const float*)d_in[3];
    const float* qxt   = (const float*)d_in[4];
    const float* kxt   = (const float*)d_in[5];
    const float* vxt   = (const float*)d_in[6];
    const float* qrt   = (const float*)d_in[7];
    const float* krt   = (const float*)d_in[8];
    const float* vrt   = (const float*)d_in[9];
    const float* pw    = (const float*)d_in[10];
    const float* pb    = (const float*)d_in[11];
    float* out = (float*)d_out;

    ushort* qb  = (ushort*)d_ws;                       // [128][8][64][32] bf16
    ushort* kb  = qb + (size_t)2097152;
    ushort* vb  = kb + (size_t)2097152;
    ushort* aob = vb + (size_t)2097152;                // [8192][256] bf16

    k_qkv<<<dim3(12, 64), 256, 0, stream>>>(feats, qkvw, qkvb, qb, kb, vb);
    k_attn<<<dim3(1024), 256, 0, stream>>>(qb, kb, vb, nco, qxt, kxt, vxt, qrt, krt, vrt, aob);
    k_proj<<<dim3(4, 64), 256, 0, stream>>>(aob, pw, pb, out);
}